// Round 1
// baseline (441.208 us; speedup 1.0000x reference)
//
#include <hip/hip_runtime.h>
#include <hip/hip_bf16.h>

// Pipeline: cast->bf16, QKV GEMM (MFMA), RMSNorm+RoPE, V-transpose,
// flash attention (causal, GQA), output GEMM. All bf16 MFMA w/ fp32 accum.

typedef __bf16 bf16;
typedef bf16 bf16x8 __attribute__((ext_vector_type(8)));
typedef bf16 bf16x4 __attribute__((ext_vector_type(4)));
typedef float f32x4 __attribute__((ext_vector_type(4)));

#define L_SEQ 2048
#define NQH 16
#define NKVH 4

// ---------------- cast fp32 -> bf16, 4 elems/thread ----------------
__global__ __launch_bounds__(256) void cast_bf16(const float* __restrict__ in,
                                                 bf16* __restrict__ out, int n) {
  int i = (blockIdx.x * 256 + threadIdx.x) * 4;
  if (i < n) {
    float4 v = *(const float4*)&in[i];
    bf16x4 o;
    o[0] = (bf16)v.x; o[1] = (bf16)v.y; o[2] = (bf16)v.z; o[3] = (bf16)v.w;
    *(bf16x4*)&out[i] = o;
  }
}

// ---------------- GEMM: C[M,N] = A[M,K] * B[N,K]^T (both row-major, K contig) ----
// 128x128 tile, BK=32, 4 waves each 64x64, 16x16x32 bf16 MFMA.
// LDS swizzle: chunk ^= (row>>1)&3  (consistent on write+read => bijective/correct)
__global__ __launch_bounds__(256)
void gemm_bt(const bf16* __restrict__ A, const bf16* __restrict__ B,
             float* __restrict__ C, int M, int N, int K) {
  __shared__ bf16 As[128 * 32];
  __shared__ bf16 Bs[128 * 32];
  const int tid = threadIdx.x;
  const int lane = tid & 63, w = tid >> 6;
  const int lq = lane & 15, g = lane >> 4;
  const int wr = w >> 1, wc = w & 1;
  const int bx = blockIdx.x, by = blockIdx.y;

  f32x4 acc[4][4] = {};

  const int nk = K >> 5;
  for (int kt = 0; kt < nk; ++kt) {
#pragma unroll
    for (int c = 0; c < 2; ++c) {
      int idx = c * 256 + tid;  // 0..511
      int row = idx >> 2;       // 0..127
      int ch = idx & 3;
      int pch = ch ^ ((row >> 1) & 3);
      bf16x8 va = *(const bf16x8*)&A[(size_t)(by * 128 + row) * K + kt * 32 + ch * 8];
      *(bf16x8*)&As[row * 32 + pch * 8] = va;
      bf16x8 vb = *(const bf16x8*)&B[(size_t)(bx * 128 + row) * K + kt * 32 + ch * 8];
      *(bf16x8*)&Bs[row * 32 + pch * 8] = vb;
    }
    __syncthreads();
    bf16x8 af[4], bfr[4];
#pragma unroll
    for (int i = 0; i < 4; ++i) {
      int ra = wr * 64 + i * 16 + lq;
      af[i] = *(const bf16x8*)&As[ra * 32 + (g ^ ((ra >> 1) & 3)) * 8];
      int rb = wc * 64 + i * 16 + lq;
      bfr[i] = *(const bf16x8*)&Bs[rb * 32 + (g ^ ((rb >> 1) & 3)) * 8];
    }
#pragma unroll
    for (int i = 0; i < 4; ++i)
#pragma unroll
      for (int j = 0; j < 4; ++j)
        acc[i][j] = __builtin_amdgcn_mfma_f32_16x16x32_bf16(af[i], bfr[j], acc[i][j], 0, 0, 0);
    __syncthreads();
  }
  // epilogue: C/D layout col=lane&15, row=(lane>>4)*4+reg  [m89-verified]
#pragma unroll
  for (int i = 0; i < 4; ++i)
#pragma unroll
    for (int j = 0; j < 4; ++j) {
      int row = by * 128 + wr * 64 + i * 16 + g * 4;
      int col = bx * 128 + wc * 64 + j * 16 + lq;
#pragma unroll
      for (int r = 0; r < 4; ++r) C[(size_t)(row + r) * N + col] = acc[i][j][r];
    }
}

// ---------------- RMSNorm + RoPE + split/scale ----------------
// one block per (b,l); wave handles one head per iteration (64 lanes = 64 dims)
__global__ __launch_bounds__(256)
void norm_rope(const float* __restrict__ qkv, const float* __restrict__ qw,
               const float* __restrict__ kw, bf16* __restrict__ Qb,
               bf16* __restrict__ Kb, bf16* __restrict__ Vb) {
  const int bl = blockIdx.x;  // b*L + l
  const int b = bl >> 11, l = bl & (L_SEQ - 1);
  const int w = threadIdx.x >> 6, lane = threadIdx.x & 63;
  const int i = lane & 31;
  // freq = 10000^(-2i/64) = exp2(-i * log2(10000)/32)
  float freq = exp2f(-(float)i * 0.41524101186280154f);
  float theta = (float)l * freq;
  float sn, cs;
  sincosf(theta, &sn, &cs);
  float qwl = qw[lane], kwl = kw[lane];

  for (int h = w; h < 24; h += 4) {
    float v = qkv[(size_t)bl * 1536 + h * 64 + lane];
    if (h < 20) {
      float ss = v * v;
#pragma unroll
      for (int off = 32; off; off >>= 1) ss += __shfl_xor(ss, off);
      float rs = rsqrtf(ss * (1.f / 64.f) + 1e-6f);
      float wt = (h < 16) ? qwl : kwl;
      float y = v * rs * wt;
      float part = __shfl_xor(y, 32);
      // lane<32: x1*cos - x2*sin ; lane>=32: x1*sin + x2*cos
      float out = (lane < 32) ? (y * cs - part * sn) : (part * sn + y * cs);
      if (h < 16)
        Qb[((size_t)(b * NQH + h) * L_SEQ + l) * 64 + lane] = (bf16)(out * 0.125f);
      else
        Kb[((size_t)(b * NKVH + (h - 16)) * L_SEQ + l) * 64 + lane] = (bf16)out;
    } else {
      Vb[((size_t)(b * NKVH + (h - 20)) * L_SEQ + l) * 64 + lane] = (bf16)v;
    }
  }
}

// ---------------- V transpose: (bk, L, 64) -> (bk, 64, L) ----------------
__global__ __launch_bounds__(256)
void transpose_v(const bf16* __restrict__ Vb, bf16* __restrict__ Vt) {
  __shared__ bf16 T[64 * 66];
  const int bk = blockIdx.y;
  const int l0 = blockIdx.x * 64;
  const int t = threadIdx.x;
  const bf16* src = Vb + (size_t)bk * L_SEQ * 64;
#pragma unroll
  for (int c = 0; c < 2; ++c) {
    int idx = c * 256 + t;
    int row = idx >> 3, ch = idx & 7;
    bf16x8 v = *(const bf16x8*)&src[(size_t)(l0 + row) * 64 + ch * 8];
#pragma unroll
    for (int j = 0; j < 8; ++j) T[(ch * 8 + j) * 66 + row] = v[j];
  }
  __syncthreads();
  bf16* dst = Vt + (size_t)bk * 64 * L_SEQ;
#pragma unroll
  for (int c = 0; c < 2; ++c) {
    int idx = c * 256 + t;
    int d = idx >> 3, ch = idx & 7;
    bf16x8 v;
#pragma unroll
    for (int j = 0; j < 8; ++j) v[j] = T[d * 66 + ch * 8 + j];
    *(bf16x8*)&dst[(size_t)d * L_SEQ + l0 + ch * 8] = v;
  }
}

// ---------------- flash attention, causal, GQA ----------------
// block = 4 waves, each wave owns 16 q rows; 32-key tiles.
// S^T = mfma(K, Q): lane holds scores for query (lane&15), keys (lane>>4)*4+r.
// P bounced via per-wave LDS into PV A-frag layout; K/V frags straight from global (L2).
__global__ __launch_bounds__(256)
void attn(const bf16* __restrict__ Qb, const bf16* __restrict__ Kb,
          const bf16* __restrict__ Vt, bf16* __restrict__ Ao) {
  const int qblk = blockIdx.x;  // 0..31
  const int bh = blockIdx.y;    // 0..31
  const int b = bh >> 4, h = bh & 15, kv = h >> 2;
  const int w = threadIdx.x >> 6, lane = threadIdx.x & 63;
  const int lq = lane & 15, g = lane >> 4;

  __shared__ bf16 Plds[4][16 * 40];  // per-wave, padded rows (80B)

  const bf16* Qp = Qb + (size_t)(b * NQH + h) * L_SEQ * 64;
  const bf16* Kp = Kb + (size_t)(b * NKVH + kv) * L_SEQ * 64;
  const bf16* Vp = Vt + (size_t)(b * NKVH + kv) * 64 * L_SEQ;

  const int qr0 = qblk * 64 + w * 16;
  bf16x8 qf[2];
  qf[0] = *(const bf16x8*)&Qp[(qr0 + lq) * 64 + g * 8];
  qf[1] = *(const bf16x8*)&Qp[(qr0 + lq) * 64 + 32 + g * 8];

  f32x4 o[4] = {};
  float m = -1e30f, lsum = 0.f;
  const float L2E = 1.4426950408889634f;

  const int nkt = qblk * 2 + 2;
  for (int kt = 0; kt < nkt; ++kt) {
    const int k0 = kt * 32;
    f32x4 s[2] = {};
#pragma unroll
    for (int ks = 0; ks < 2; ++ks) {
      const bf16* kr = &Kp[(size_t)(k0 + ks * 16 + lq) * 64 + g * 8];
      s[ks] = __builtin_amdgcn_mfma_f32_16x16x32_bf16(*(const bf16x8*)kr, qf[0], s[ks], 0, 0, 0);
      s[ks] = __builtin_amdgcn_mfma_f32_16x16x32_bf16(*(const bf16x8*)(kr + 32), qf[1], s[ks], 0, 0, 0);
    }
    const int qg = qr0 + lq;
    float sv[8];
    float tmax = -1e30f;
#pragma unroll
    for (int ks = 0; ks < 2; ++ks)
#pragma unroll
      for (int r = 0; r < 4; ++r) {
        int key = k0 + ks * 16 + g * 4 + r;
        float x = s[ks][r];
        if (key > qg) x = -1e30f;  // causal (== ref's -1e9 mask: exp underflows to 0)
        sv[ks * 4 + r] = x;
        tmax = fmaxf(tmax, x);
      }
    tmax = fmaxf(tmax, __shfl_xor(tmax, 16));
    tmax = fmaxf(tmax, __shfl_xor(tmax, 32));
    float mnew = fmaxf(m, tmax);
    float alpha = exp2f((m - mnew) * L2E);
    m = mnew;
    float rsum = 0.f;
    bf16x4 p0, p1;
#pragma unroll
    for (int r = 0; r < 4; ++r) {
      float pa = exp2f((sv[r] - mnew) * L2E);
      float pb = exp2f((sv[4 + r] - mnew) * L2E);
      rsum += pa + pb;
      p0[r] = (bf16)pa;
      p1[r] = (bf16)pb;
    }
    rsum += __shfl_xor(rsum, 16);
    rsum += __shfl_xor(rsum, 32);
    lsum = lsum * alpha + rsum;
    // P[q=lq][key]: frag ks keys at ks*16 + g*4..+3
    *(bf16x4*)&Plds[w][lq * 40 + g * 4] = p0;
    *(bf16x4*)&Plds[w][lq * 40 + 16 + g * 4] = p1;
    // rescale O (O rows are queries g*4+r; alpha lives at lane with lq==row)
    float ar[4];
#pragma unroll
    for (int r = 0; r < 4; ++r) ar[r] = __shfl(alpha, (lane & 48) | (g * 4 + r));
#pragma unroll
    for (int dt = 0; dt < 4; ++dt)
#pragma unroll
      for (int r = 0; r < 4; ++r) o[dt][r] *= ar[r];
    bf16x8 pf = *(const bf16x8*)&Plds[w][lq * 40 + g * 8];
#pragma unroll
    for (int dt = 0; dt < 4; ++dt) {
      bf16x8 vf = *(const bf16x8*)&Vp[(size_t)(dt * 16 + lq) * L_SEQ + k0 + g * 8];
      o[dt] = __builtin_amdgcn_mfma_f32_16x16x32_bf16(pf, vf, o[dt], 0, 0, 0);
    }
  }
  float linv = 1.f / lsum;
#pragma unroll
  for (int r = 0; r < 4; ++r) {
    float li = __shfl(linv, (lane & 48) | (g * 4 + r));
    int row = b * L_SEQ + qr0 + g * 4 + r;
#pragma unroll
    for (int dt = 0; dt < 4; ++dt)
      Ao[(size_t)row * 1024 + h * 64 + dt * 16 + lq] = (bf16)(o[dt][r] * li);
  }
}

extern "C" void kernel_launch(void* const* d_in, const int* in_sizes, int n_in,
                              void* d_out, int out_size, void* d_ws, size_t ws_size,
                              hipStream_t stream) {
  const float* x = (const float*)d_in[0];
  const float* Wqkv = (const float*)d_in[1];
  const float* Wout = (const float*)d_in[2];
  const float* qw = (const float*)d_in[3];
  const float* kw = (const float*)d_in[4];
  // d_in[5] = mask: causal, implemented analytically
  float* out = (float*)d_out;

  char* ws = (char*)d_ws;
  size_t off = 0;
  auto alloc = [&](size_t bytes) {
    void* p = ws + off;
    off = (off + bytes + 255) & ~(size_t)255;
    return p;
  };
  bf16* xb = (bf16*)alloc(8388608ull * 2);    // x bf16 (4096 x 2048)
  bf16* wqb = (bf16*)alloc(3145728ull * 2);   // W_qkv bf16 (1536 x 2048)
  bf16* wob = (bf16*)alloc(2097152ull * 2);   // W_out bf16 (2048 x 1024)
  float* qkv = (float*)alloc(4096ull * 1536 * 4);
  bf16* Qb = (bf16*)alloc(4194304ull * 2);    // (2,16,2048,64)
  bf16* Kb = (bf16*)alloc(1048576ull * 2);    // (2,4,2048,64)
  bf16* Vb = (bf16*)alloc(1048576ull * 2);
  bf16* Vt = (bf16*)alloc(1048576ull * 2);    // (2*4, 64, 2048)
  bf16* Ao = (bf16*)alloc(4194304ull * 2);    // (4096, 1024)

  cast_bf16<<<8192, 256, 0, stream>>>(x, xb, 8388608);
  cast_bf16<<<3072, 256, 0, stream>>>(Wqkv, wqb, 3145728);
  cast_bf16<<<2048, 256, 0, stream>>>(Wout, wob, 2097152);
  gemm_bt<<<dim3(12, 32), 256, 0, stream>>>(xb, wqb, qkv, 4096, 1536, 2048);
  norm_rope<<<4096, 256, 0, stream>>>(qkv, qw, kw, Qb, Kb, Vb);
  transpose_v<<<dim3(32, 8), 256, 0, stream>>>(Vb, Vt);
  attn<<<dim3(32, 32), 256, 0, stream>>>(Qb, Kb, Vt, Ao);
  gemm_bt<<<dim3(16, 32), 256, 0, stream>>>(Ao, wob, out, 4096, 2048, 1024);
}

// Round 3
// 303.483 us; speedup vs baseline: 1.4538x; 1.4538x over previous
//
#include <hip/hip_runtime.h>
#include <hip/hip_bf16.h>

// Pipeline: cast->bf16, QKV GEMM (MFMA), RMSNorm+RoPE, V-transpose,
// flash attention (causal, GQA, LDS-staged KV), output GEMM.

typedef __bf16 bf16;
typedef bf16 bf16x8 __attribute__((ext_vector_type(8)));
typedef bf16 bf16x4 __attribute__((ext_vector_type(4)));
typedef float f32x4 __attribute__((ext_vector_type(4)));

#define L_SEQ 2048
#define NQH 16
#define NKVH 4

// ---------------- cast fp32 -> bf16, 4 elems/thread ----------------
__global__ __launch_bounds__(256) void cast_bf16(const float* __restrict__ in,
                                                 bf16* __restrict__ out, int n) {
  int i = (blockIdx.x * 256 + threadIdx.x) * 4;
  if (i < n) {
    float4 v = *(const float4*)&in[i];
    bf16x4 o;
    o[0] = (bf16)v.x; o[1] = (bf16)v.y; o[2] = (bf16)v.z; o[3] = (bf16)v.w;
    *(bf16x4*)&out[i] = o;
  }
}

// ---------------- GEMM: C[M,N] = A[M,K] * B[N,K]^T ----------------
__global__ __launch_bounds__(256)
void gemm_bt(const bf16* __restrict__ A, const bf16* __restrict__ B,
             float* __restrict__ C, int M, int N, int K) {
  __shared__ bf16 As[128 * 32];
  __shared__ bf16 Bs[128 * 32];
  const int tid = threadIdx.x;
  const int lane = tid & 63, w = tid >> 6;
  const int lq = lane & 15, g = lane >> 4;
  const int wr = w >> 1, wc = w & 1;
  const int bx = blockIdx.x, by = blockIdx.y;

  f32x4 acc[4][4] = {};

  const int nk = K >> 5;
  for (int kt = 0; kt < nk; ++kt) {
#pragma unroll
    for (int c = 0; c < 2; ++c) {
      int idx = c * 256 + tid;  // 0..511
      int row = idx >> 2;       // 0..127
      int ch = idx & 3;
      int pch = ch ^ ((row >> 1) & 3);
      bf16x8 va = *(const bf16x8*)&A[(size_t)(by * 128 + row) * K + kt * 32 + ch * 8];
      *(bf16x8*)&As[row * 32 + pch * 8] = va;
      bf16x8 vb = *(const bf16x8*)&B[(size_t)(bx * 128 + row) * K + kt * 32 + ch * 8];
      *(bf16x8*)&Bs[row * 32 + pch * 8] = vb;
    }
    __syncthreads();
    bf16x8 af[4], bfr[4];
#pragma unroll
    for (int i = 0; i < 4; ++i) {
      int ra = wr * 64 + i * 16 + lq;
      af[i] = *(const bf16x8*)&As[ra * 32 + (g ^ ((ra >> 1) & 3)) * 8];
      int rb = wc * 64 + i * 16 + lq;
      bfr[i] = *(const bf16x8*)&Bs[rb * 32 + (g ^ ((rb >> 1) & 3)) * 8];
    }
#pragma unroll
    for (int i = 0; i < 4; ++i)
#pragma unroll
      for (int j = 0; j < 4; ++j)
        acc[i][j] = __builtin_amdgcn_mfma_f32_16x16x32_bf16(af[i], bfr[j], acc[i][j], 0, 0, 0);
    __syncthreads();
  }
#pragma unroll
  for (int i = 0; i < 4; ++i)
#pragma unroll
    for (int j = 0; j < 4; ++j) {
      int row = by * 128 + wr * 64 + i * 16 + g * 4;
      int col = bx * 128 + wc * 64 + j * 16 + lq;
#pragma unroll
      for (int r = 0; r < 4; ++r) C[(size_t)(row + r) * N + col] = acc[i][j][r];
    }
}

// ---------------- RMSNorm + RoPE + split/scale ----------------
__global__ __launch_bounds__(256)
void norm_rope(const float* __restrict__ qkv, const float* __restrict__ qw,
               const float* __restrict__ kw, bf16* __restrict__ Qb,
               bf16* __restrict__ Kb, bf16* __restrict__ Vb) {
  const int bl = blockIdx.x;  // b*L + l
  const int b = bl >> 11, l = bl & (L_SEQ - 1);
  const int w = threadIdx.x >> 6, lane = threadIdx.x & 63;
  const int i = lane & 31;
  float freq = exp2f(-(float)i * 0.41524101186280154f);
  float theta = (float)l * freq;
  float sn, cs;
  sincosf(theta, &sn, &cs);
  float qwl = qw[lane], kwl = kw[lane];

  for (int h = w; h < 24; h += 4) {
    float v = qkv[(size_t)bl * 1536 + h * 64 + lane];
    if (h < 20) {
      float ss = v * v;
#pragma unroll
      for (int off = 32; off; off >>= 1) ss += __shfl_xor(ss, off);
      float rs = rsqrtf(ss * (1.f / 64.f) + 1e-6f);
      float wt = (h < 16) ? qwl : kwl;
      float y = v * rs * wt;
      float part = __shfl_xor(y, 32);
      float out = (lane < 32) ? (y * cs - part * sn) : (part * sn + y * cs);
      if (h < 16)
        Qb[((size_t)(b * NQH + h) * L_SEQ + l) * 64 + lane] = (bf16)(out * 0.125f);
      else
        Kb[((size_t)(b * NKVH + (h - 16)) * L_SEQ + l) * 64 + lane] = (bf16)out;
    } else {
      Vb[((size_t)(b * NKVH + (h - 20)) * L_SEQ + l) * 64 + lane] = (bf16)v;
    }
  }
}

// ---------------- V transpose: (bk, L, 64) -> (bk, 64, L) ----------------
__global__ __launch_bounds__(256)
void transpose_v(const bf16* __restrict__ Vb, bf16* __restrict__ Vt) {
  __shared__ bf16 T[64 * 66];
  const int bk = blockIdx.y;
  const int l0 = blockIdx.x * 64;
  const int t = threadIdx.x;
  const bf16* src = Vb + (size_t)bk * L_SEQ * 64;
#pragma unroll
  for (int c = 0; c < 2; ++c) {
    int idx = c * 256 + t;
    int row = idx >> 3, ch = idx & 7;
    bf16x8 v = *(const bf16x8*)&src[(size_t)(l0 + row) * 64 + ch * 8];
#pragma unroll
    for (int j = 0; j < 8; ++j) T[(ch * 8 + j) * 66 + row] = v[j];
  }
  __syncthreads();
  bf16* dst = Vt + (size_t)bk * 64 * L_SEQ;
#pragma unroll
  for (int c = 0; c < 2; ++c) {
    int idx = c * 256 + t;
    int d = idx >> 3, ch = idx & 7;
    bf16x8 v;
#pragma unroll
    for (int j = 0; j < 8; ++j) v[j] = T[d * 66 + ch * 8 + j];
    *(bf16x8*)&dst[(size_t)d * L_SEQ + l0 + ch * 8] = v;
  }
}

// ---------------- flash attention, causal, GQA, LDS-staged KV ----------------
// block = 4 waves, each wave owns 16 q rows; 64-key tiles staged in LDS
// (shared by all 4 waves), single-buffered with T14 async split:
// issue next tile's global loads -> regs BEFORE compute, ds_write after barrier.
// LDS rows (128B) XOR-swizzled: chunk ^= row&7  => conflict-free ds_read_b128.
__global__ __launch_bounds__(256)
void attn(const bf16* __restrict__ Qb, const bf16* __restrict__ Kb,
          const bf16* __restrict__ Vt, bf16* __restrict__ Ao) {
  const int qblk = 31 - blockIdx.x;  // longest-first
  const int bh = blockIdx.y;         // 0..31
  const int b = bh >> 4, h = bh & 15, kv = h >> 2;
  const int tid = threadIdx.x;
  const int w = tid >> 6, lane = tid & 63;
  const int lq = lane & 15, g = lane >> 4;

  __shared__ bf16 Ks[64][64];       // [key][dim], swizzled chunks
  __shared__ bf16 Vs[64][64];       // [dim][key], swizzled chunks
  __shared__ bf16 Plds[4][16][72];  // per-wave P bounce

  const bf16* Qp = Qb + (size_t)(b * NQH + h) * L_SEQ * 64;
  const bf16* Kp = Kb + (size_t)(b * NKVH + kv) * L_SEQ * 64;
  const bf16* Vp = Vt + (size_t)(b * NKVH + kv) * 64 * L_SEQ;

  const int qr0 = qblk * 64 + w * 16;
  bf16x8 qf[2];
  qf[0] = *(const bf16x8*)&Qp[(qr0 + lq) * 64 + g * 8];
  qf[1] = *(const bf16x8*)&Qp[(qr0 + lq) * 64 + 32 + g * 8];

  // staging thread mapping: 512 chunk-slots of 16B; r = idx>>3 (row), c = idx&7
  const int sr0 = tid >> 3, sc = tid & 7;
  const int sr1 = sr0 + 32;
  const int swc0 = (sc ^ (sr0 & 7)) * 8;  // sr1&7 == sr0&7
  bf16x8 rk0, rk1, rv0, rv1;

  auto load_tile = [&](int k0) {
    rk0 = *(const bf16x8*)&Kp[(size_t)(k0 + sr0) * 64 + sc * 8];
    rk1 = *(const bf16x8*)&Kp[(size_t)(k0 + sr1) * 64 + sc * 8];
    rv0 = *(const bf16x8*)&Vp[(size_t)sr0 * L_SEQ + k0 + sc * 8];
    rv1 = *(const bf16x8*)&Vp[(size_t)sr1 * L_SEQ + k0 + sc * 8];
  };
  auto write_tile = [&]() {
    *(bf16x8*)&Ks[sr0][swc0] = rk0;
    *(bf16x8*)&Ks[sr1][swc0] = rk1;
    *(bf16x8*)&Vs[sr0][swc0] = rv0;
    *(bf16x8*)&Vs[sr1][swc0] = rv1;
  };

  f32x4 o[4] = {};
  float m = -1e30f, lsum = 0.f;
  const float L2E = 1.4426950408889634f;
  const int qg = qr0 + lq;  // this lane's query row (global)

  const int nkt = qblk + 1;
  load_tile(0);
  write_tile();
  __syncthreads();

  for (int kt = 0; kt < nkt; ++kt) {
    const int k0 = kt * 64;
    const bool diag = (kt == nkt - 1);
    if (kt + 1 < nkt) load_tile(k0 + 64);  // async: hides under compute

    // ---- QK^T: s[ks] holds scores for query lq, keys k0+ks*16+g*4+r ----
    f32x4 s[4] = {};
#pragma unroll
    for (int ks = 0; ks < 4; ++ks) {
      if (!diag || ks <= w) {  // skip fully-masked frags on diag tile
        const int row = ks * 16 + lq, sw = lq & 7;
        bf16x8 kf0 = *(const bf16x8*)&Ks[row][(g ^ sw) * 8];
        bf16x8 kf1 = *(const bf16x8*)&Ks[row][((g + 4) ^ sw) * 8];
        s[ks] = __builtin_amdgcn_mfma_f32_16x16x32_bf16(kf0, qf[0], s[ks], 0, 0, 0);
        s[ks] = __builtin_amdgcn_mfma_f32_16x16x32_bf16(kf1, qf[1], s[ks], 0, 0, 0);
      }
    }
    // ---- mask (diag tile only) + online softmax ----
    if (diag) {
#pragma unroll
      for (int ks = 0; ks < 4; ++ks)
#pragma unroll
        for (int r = 0; r < 4; ++r)
          if (k0 + ks * 16 + g * 4 + r > qg) s[ks][r] = -1e30f;
    }
    float tmax = -1e30f;
#pragma unroll
    for (int ks = 0; ks < 4; ++ks)
#pragma unroll
      for (int r = 0; r < 4; ++r) tmax = fmaxf(tmax, s[ks][r]);
    tmax = fmaxf(tmax, __shfl_xor(tmax, 16));
    tmax = fmaxf(tmax, __shfl_xor(tmax, 32));
    float mnew = fmaxf(m, tmax);
    float alpha = exp2f((m - mnew) * L2E);
    m = mnew;
    float rsum = 0.f;
#pragma unroll
    for (int ks = 0; ks < 4; ++ks) {
      bf16x4 p;
#pragma unroll
      for (int r = 0; r < 4; ++r) {
        float pv = exp2f((s[ks][r] - mnew) * L2E);
        rsum += pv;
        p[r] = (bf16)pv;
      }
      *(bf16x4*)&Plds[w][lq][ks * 16 + g * 4] = p;
    }
    rsum += __shfl_xor(rsum, 16);
    rsum += __shfl_xor(rsum, 32);
    lsum = lsum * alpha + rsum;

    // ---- rescale O (rows are queries g*4+r) ----
    float ar[4];
#pragma unroll
    for (int r = 0; r < 4; ++r) ar[r] = __shfl(alpha, (lane & 48) | (g * 4 + r));
#pragma unroll
    for (int dt = 0; dt < 4; ++dt)
#pragma unroll
      for (int r = 0; r < 4; ++r) o[dt][r] *= ar[r];

    // ---- PV: o[dt] += P[16x64] * V[64 keys, dims dt*16..+15] ----
    bf16x8 pf0 = *(const bf16x8*)&Plds[w][lq][g * 8];
    bf16x8 pf1 = *(const bf16x8*)&Plds[w][lq][32 + g * 8];
#pragma unroll
    for (int dt = 0; dt < 4; ++dt) {
      const int row = dt * 16 + lq, sw = lq & 7;
      bf16x8 vf0 = *(const bf16x8*)&Vs[row][(g ^ sw) * 8];
      o[dt] = __builtin_amdgcn_mfma_f32_16x16x32_bf16(pf0, vf0, o[dt], 0, 0, 0);
      if (!diag || w >= 2) {
        bf16x8 vf1 = *(const bf16x8*)&Vs[row][((g + 4) ^ sw) * 8];
        o[dt] = __builtin_amdgcn_mfma_f32_16x16x32_bf16(pf1, vf1, o[dt], 0, 0, 0);
      }
    }

    if (kt + 1 < nkt) {
      __syncthreads();   // all waves done reading LDS tile kt
      write_tile();      // vmcnt wait + ds_write of tile kt+1
      __syncthreads();   // tile kt+1 visible
    }
  }

  float linv = 1.f / lsum;
#pragma unroll
  for (int r = 0; r < 4; ++r) {
    float li = __shfl(linv, (lane & 48) | (g * 4 + r));
    int row = b * L_SEQ + qr0 + g * 4 + r;
#pragma unroll
    for (int dt = 0; dt < 4; ++dt)
      Ao[(size_t)row * 1024 + h * 64 + dt * 16 + lq] = (bf16)(o[dt][r] * li);
  }
}

extern "C" void kernel_launch(void* const* d_in, const int* in_sizes, int n_in,
                              void* d_out, int out_size, void* d_ws, size_t ws_size,
                              hipStream_t stream) {
  const float* x = (const float*)d_in[0];
  const float* Wqkv = (const float*)d_in[1];
  const float* Wout = (const float*)d_in[2];
  const float* qw = (const float*)d_in[3];
  const float* kw = (const float*)d_in[4];
  float* out = (float*)d_out;

  char* ws = (char*)d_ws;
  size_t off = 0;
  auto alloc = [&](size_t bytes) {
    void* p = ws + off;
    off = (off + bytes + 255) & ~(size_t)255;
    return p;
  };
  bf16* xb = (bf16*)alloc(8388608ull * 2);
  bf16* wqb = (bf16*)alloc(3145728ull * 2);
  bf16* wob = (bf16*)alloc(2097152ull * 2);
  float* qkv = (float*)alloc(4096ull * 1536 * 4);
  bf16* Qb = (bf16*)alloc(4194304ull * 2);
  bf16* Kb = (bf16*)alloc(1048576ull * 2);
  bf16* Vb = (bf16*)alloc(1048576ull * 2);
  bf16* Vt = (bf16*)alloc(1048576ull * 2);
  bf16* Ao = (bf16*)alloc(4194304ull * 2);

  cast_bf16<<<8192, 256, 0, stream>>>(x, xb, 8388608);
  cast_bf16<<<3072, 256, 0, stream>>>(Wqkv, wqb, 3145728);
  cast_bf16<<<2048, 256, 0, stream>>>(Wout, wob, 2097152);
  gemm_bt<<<dim3(12, 32), 256, 0, stream>>>(xb, wqb, qkv, 4096, 1536, 2048);
  norm_rope<<<4096, 256, 0, stream>>>(qkv, qw, kw, Qb, Kb, Vb);
  transpose_v<<<dim3(32, 8), 256, 0, stream>>>(Vb, Vt);
  attn<<<dim3(32, 32), 256, 0, stream>>>(Qb, Kb, Vt, Ao);
  gemm_bt<<<dim3(16, 32), 256, 0, stream>>>(Ao, wob, out, 4096, 2048, 1024);
}

// Round 5
// 282.471 us; speedup vs baseline: 1.5620x; 1.0744x over previous
//
#include <hip/hip_runtime.h>
#include <hip/hip_bf16.h>

// Pipeline: cast->bf16, QKV GEMM (MFMA + global_load_lds), RMSNorm+RoPE,
// V-transpose, flash attention (causal, GQA, LDS-staged KV, paired q-tiles),
// output GEMM.

typedef __bf16 bf16;
typedef bf16 bf16x8 __attribute__((ext_vector_type(8)));
typedef bf16 bf16x4 __attribute__((ext_vector_type(4)));
typedef float f32x4 __attribute__((ext_vector_type(4)));

#define L_SEQ 2048
#define NQH 16
#define NKVH 4

// async global->LDS 16B DMA (gfx950). LDS dest is wave-uniform base + lane*16.
typedef __attribute__((address_space(3))) void lds_void;
typedef const __attribute__((address_space(1))) void glb_void;
__device__ __forceinline__ void async_ld16(const void* g, void* l) {
  __builtin_amdgcn_global_load_lds((glb_void*)g, (lds_void*)l, 16, 0, 0);
}

// ---------------- cast fp32 -> bf16, 4 elems/thread ----------------
__global__ __launch_bounds__(256) void cast_bf16(const float* __restrict__ in,
                                                 bf16* __restrict__ out, int n) {
  int i = (blockIdx.x * 256 + threadIdx.x) * 4;
  if (i < n) {
    float4 v = *(const float4*)&in[i];
    bf16x4 o;
    o[0] = (bf16)v.x; o[1] = (bf16)v.y; o[2] = (bf16)v.z; o[3] = (bf16)v.w;
    *(bf16x4*)&out[i] = o;
  }
}

// ---------------- GEMM: C[M,N] = A[M,K] * B[N,K]^T ----------------
// 128x128 tile, BK=32, 4 waves each 64x64, 16x16x32 bf16 MFMA.
// Staging via global_load_lds w=16: LDS linear dest, source chunk pre-swizzled
// (LDS[row][c] holds chunk c ^ ((row>>1)&3)); reads apply the same XOR.
__global__ __launch_bounds__(256)
void gemm_bt(const bf16* __restrict__ A, const bf16* __restrict__ B,
             float* __restrict__ C, int M, int N, int K) {
  __shared__ bf16 As[128 * 32];
  __shared__ bf16 Bs[128 * 32];
  const int tid = threadIdx.x;
  const int lane = tid & 63, w = tid >> 6;
  const int lq = lane & 15, g = lane >> 4;
  const int wr = w >> 1, wc = w & 1;
  const int bx = blockIdx.x, by = blockIdx.y;

  // per-c staging source pointers (chunk index pre-swizzled) + LDS wave bases
  const bf16* gA[2];
  const bf16* gB[2];
  bf16* ldsA[2];
  bf16* ldsB[2];
#pragma unroll
  for (int c = 0; c < 2; ++c) {
    int slot = c * 256 + tid;
    int row = slot >> 2, ch = slot & 3;
    int sch = ch ^ ((row >> 1) & 3);
    gA[c] = &A[(size_t)(by * 128 + row) * K + sch * 8];
    gB[c] = &B[(size_t)(bx * 128 + row) * K + sch * 8];
    int wbase = (c * 256 + w * 64) * 8;  // wave-uniform LDS base (elements)
    ldsA[c] = &As[wbase];
    ldsB[c] = &Bs[wbase];
  }

  f32x4 acc[4][4] = {};

  const int nk = K >> 5;
  for (int kt = 0; kt < nk; ++kt) {
#pragma unroll
    for (int c = 0; c < 2; ++c) {
      async_ld16(gA[c] + kt * 32, ldsA[c]);
      async_ld16(gB[c] + kt * 32, ldsB[c]);
    }
    __syncthreads();  // drains vmcnt -> LDS tile visible
    bf16x8 af[4], bfr[4];
#pragma unroll
    for (int i = 0; i < 4; ++i) {
      int ra = wr * 64 + i * 16 + lq;
      af[i] = *(const bf16x8*)&As[ra * 32 + (g ^ ((ra >> 1) & 3)) * 8];
      int rb = wc * 64 + i * 16 + lq;
      bfr[i] = *(const bf16x8*)&Bs[rb * 32 + (g ^ ((rb >> 1) & 3)) * 8];
    }
#pragma unroll
    for (int i = 0; i < 4; ++i)
#pragma unroll
      for (int j = 0; j < 4; ++j)
        acc[i][j] = __builtin_amdgcn_mfma_f32_16x16x32_bf16(af[i], bfr[j], acc[i][j], 0, 0, 0);
    __syncthreads();
  }
#pragma unroll
  for (int i = 0; i < 4; ++i)
#pragma unroll
    for (int j = 0; j < 4; ++j) {
      int row = by * 128 + wr * 64 + i * 16 + g * 4;
      int col = bx * 128 + wc * 64 + j * 16 + lq;
#pragma unroll
      for (int r = 0; r < 4; ++r) C[(size_t)(row + r) * N + col] = acc[i][j][r];
    }
}

// ---------------- RMSNorm + RoPE + split/scale ----------------
__global__ __launch_bounds__(256)
void norm_rope(const float* __restrict__ qkv, const float* __restrict__ qw,
               const float* __restrict__ kw, bf16* __restrict__ Qb,
               bf16* __restrict__ Kb, bf16* __restrict__ Vb) {
  const int bl = blockIdx.x;  // b*L + l
  const int b = bl >> 11, l = bl & (L_SEQ - 1);
  const int w = threadIdx.x >> 6, lane = threadIdx.x & 63;
  const int i = lane & 31;
  float freq = exp2f(-(float)i * 0.41524101186280154f);
  float theta = (float)l * freq;
  float sn, cs;
  sincosf(theta, &sn, &cs);
  float qwl = qw[lane], kwl = kw[lane];

  for (int h = w; h < 24; h += 4) {
    float v = qkv[(size_t)bl * 1536 + h * 64 + lane];
    if (h < 20) {
      float ss = v * v;
#pragma unroll
      for (int off = 32; off; off >>= 1) ss += __shfl_xor(ss, off);
      float rs = rsqrtf(ss * (1.f / 64.f) + 1e-6f);
      float wt = (h < 16) ? qwl : kwl;
      float y = v * rs * wt;
      float part = __shfl_xor(y, 32);
      float out = (lane < 32) ? (y * cs - part * sn) : (part * sn + y * cs);
      if (h < 16)
        Qb[((size_t)(b * NQH + h) * L_SEQ + l) * 64 + lane] = (bf16)(out * 0.125f);
      else
        Kb[((size_t)(b * NKVH + (h - 16)) * L_SEQ + l) * 64 + lane] = (bf16)out;
    } else {
      Vb[((size_t)(b * NKVH + (h - 20)) * L_SEQ + l) * 64 + lane] = (bf16)v;
    }
  }
}

// ---------------- V transpose: (bk, L, 64) -> (bk, 64, L) ----------------
__global__ __launch_bounds__(256)
void transpose_v(const bf16* __restrict__ Vb, bf16* __restrict__ Vt) {
  __shared__ bf16 T[64 * 66];
  const int bk = blockIdx.y;
  const int l0 = blockIdx.x * 64;
  const int t = threadIdx.x;
  const bf16* src = Vb + (size_t)bk * L_SEQ * 64;
#pragma unroll
  for (int c = 0; c < 2; ++c) {
    int idx = c * 256 + t;
    int row = idx >> 3, ch = idx & 7;
    bf16x8 v = *(const bf16x8*)&src[(size_t)(l0 + row) * 64 + ch * 8];
#pragma unroll
    for (int j = 0; j < 8; ++j) T[(ch * 8 + j) * 66 + row] = v[j];
  }
  __syncthreads();
  bf16* dst = Vt + (size_t)bk * 64 * L_SEQ;
#pragma unroll
  for (int c = 0; c < 2; ++c) {
    int idx = c * 256 + t;
    int d = idx >> 3, ch = idx & 7;
    bf16x8 v;
#pragma unroll
    for (int j = 0; j < 8; ++j) v[j] = T[d * 66 + ch * 8 + j];
    *(bf16x8*)&dst[(size_t)d * L_SEQ + l0 + ch * 8] = v;
  }
}

// ---------------- flash attention, causal, GQA, LDS-staged KV ----------------
// block = 4 waves, 16 q-rows/wave; 64-key LDS tiles (T14 async-split staging,
// XOR-swizzled rows). Each block processes the q-tile PAIR (p, 31-p) serially
// => uniform 33 key-tiles/block, grid 16x32, no triangular tail.
__global__ __launch_bounds__(256)
void attn(const bf16* __restrict__ Qb, const bf16* __restrict__ Kb,
          const bf16* __restrict__ Vt, bf16* __restrict__ Ao) {
  const int pair = blockIdx.x;  // 0..15
  const int bh = blockIdx.y;    // 0..31
  const int b = bh >> 4, h = bh & 15, kv = h >> 2;
  const int tid = threadIdx.x;
  const int w = tid >> 6, lane = tid & 63;
  const int lq = lane & 15, g = lane >> 4;

  __shared__ bf16 Ks[64][64];       // [key][dim], swizzled chunks
  __shared__ bf16 Vs[64][64];       // [dim][key], swizzled chunks
  __shared__ bf16 Plds[4][16][72];  // per-wave P bounce

  const bf16* Qp = Qb + (size_t)(b * NQH + h) * L_SEQ * 64;
  const bf16* Kp = Kb + (size_t)(b * NKVH + kv) * L_SEQ * 64;
  const bf16* Vp = Vt + (size_t)(b * NKVH + kv) * 64 * L_SEQ;

  // staging thread mapping: 512 chunk-slots of 16B; r = idx>>3 (row), c = idx&7
  const int sr0 = tid >> 3, sc = tid & 7;
  const int sr1 = sr0 + 32;
  const int swc0 = (sc ^ (sr0 & 7)) * 8;  // sr1&7 == sr0&7
  bf16x8 rk0, rk1, rv0, rv1;

  auto load_tile = [&](int k0) {
    rk0 = *(const bf16x8*)&Kp[(size_t)(k0 + sr0) * 64 + sc * 8];
    rk1 = *(const bf16x8*)&Kp[(size_t)(k0 + sr1) * 64 + sc * 8];
    rv0 = *(const bf16x8*)&Vp[(size_t)sr0 * L_SEQ + k0 + sc * 8];
    rv1 = *(const bf16x8*)&Vp[(size_t)sr1 * L_SEQ + k0 + sc * 8];
  };
  auto write_tile = [&]() {
    *(bf16x8*)&Ks[sr0][swc0] = rk0;
    *(bf16x8*)&Ks[sr1][swc0] = rk1;
    *(bf16x8*)&Vs[sr0][swc0] = rv0;
    *(bf16x8*)&Vs[sr1][swc0] = rv1;
  };

  const float L2E = 1.4426950408889634f;

  for (int half = 0; half < 2; ++half) {
    const int qblk = half ? (31 - pair) : pair;
    const int qr0 = qblk * 64 + w * 16;
    const int qg = qr0 + lq;  // this lane's query row (global)

    bf16x8 qf[2];
    qf[0] = *(const bf16x8*)&Qp[(qr0 + lq) * 64 + g * 8];
    qf[1] = *(const bf16x8*)&Qp[(qr0 + lq) * 64 + 32 + g * 8];

    f32x4 o[4] = {};
    float m = -1e30f, lsum = 0.f;

    const int nkt = qblk + 1;
    load_tile(0);
    __syncthreads();  // prior half's LDS readers done before overwrite
    write_tile();
    __syncthreads();

    for (int kt = 0; kt < nkt; ++kt) {
      const int k0 = kt * 64;
      const bool diag = (kt == nkt - 1);
      if (kt + 1 < nkt) load_tile(k0 + 64);  // async: hides under compute

      // ---- QK^T: s[ks] holds scores for query lq, keys k0+ks*16+g*4+r ----
      f32x4 s[4] = {};
#pragma unroll
      for (int ks = 0; ks < 4; ++ks) {
        if (!diag || ks <= w) {  // skip fully-masked frags on diag tile
          const int row = ks * 16 + lq, sw = lq & 7;
          bf16x8 kf0 = *(const bf16x8*)&Ks[row][(g ^ sw) * 8];
          bf16x8 kf1 = *(const bf16x8*)&Ks[row][((g + 4) ^ sw) * 8];
          s[ks] = __builtin_amdgcn_mfma_f32_16x16x32_bf16(kf0, qf[0], s[ks], 0, 0, 0);
          s[ks] = __builtin_amdgcn_mfma_f32_16x16x32_bf16(kf1, qf[1], s[ks], 0, 0, 0);
        }
      }
      // ---- mask (diag tile only) + online softmax ----
      if (diag) {
#pragma unroll
        for (int ks = 0; ks < 4; ++ks)
#pragma unroll
          for (int r = 0; r < 4; ++r)
            if (k0 + ks * 16 + g * 4 + r > qg) s[ks][r] = -1e30f;
      }
      float tmax = -1e30f;
#pragma unroll
      for (int ks = 0; ks < 4; ++ks)
#pragma unroll
        for (int r = 0; r < 4; ++r) tmax = fmaxf(tmax, s[ks][r]);
      tmax = fmaxf(tmax, __shfl_xor(tmax, 16));
      tmax = fmaxf(tmax, __shfl_xor(tmax, 32));
      float mnew = fmaxf(m, tmax);
      float alpha = exp2f((m - mnew) * L2E);
      m = mnew;
      float rsum = 0.f;
#pragma unroll
      for (int ks = 0; ks < 4; ++ks) {
        bf16x4 p;
#pragma unroll
        for (int r = 0; r < 4; ++r) {
          float pv = exp2f((s[ks][r] - mnew) * L2E);
          rsum += pv;
          p[r] = (bf16)pv;
        }
        *(bf16x4*)&Plds[w][lq][ks * 16 + g * 4] = p;
      }
      rsum += __shfl_xor(rsum, 16);
      rsum += __shfl_xor(rsum, 32);
      lsum = lsum * alpha + rsum;

      // ---- rescale O (rows are queries g*4+r) ----
      float ar[4];
#pragma unroll
      for (int r = 0; r < 4; ++r) ar[r] = __shfl(alpha, (lane & 48) | (g * 4 + r));
#pragma unroll
      for (int dt = 0; dt < 4; ++dt)
#pragma unroll
        for (int r = 0; r < 4; ++r) o[dt][r] *= ar[r];

      // ---- PV: o[dt] += P[16x64] * V[64 keys, dims dt*16..+15] ----
      bf16x8 pf0 = *(const bf16x8*)&Plds[w][lq][g * 8];
      bf16x8 pf1 = *(const bf16x8*)&Plds[w][lq][32 + g * 8];
#pragma unroll
      for (int dt = 0; dt < 4; ++dt) {
        const int row = dt * 16 + lq, sw = lq & 7;
        bf16x8 vf0 = *(const bf16x8*)&Vs[row][(g ^ sw) * 8];
        o[dt] = __builtin_amdgcn_mfma_f32_16x16x32_bf16(pf0, vf0, o[dt], 0, 0, 0);
        if (!diag || w >= 2) {
          bf16x8 vf1 = *(const bf16x8*)&Vs[row][((g + 4) ^ sw) * 8];
          o[dt] = __builtin_amdgcn_mfma_f32_16x16x32_bf16(pf1, vf1, o[dt], 0, 0, 0);
        }
      }

      if (kt + 1 < nkt) {
        __syncthreads();   // all waves done reading LDS tile kt
        write_tile();      // vmcnt wait + ds_write of tile kt+1
        __syncthreads();   // tile kt+1 visible
      }
    }

    float linv = 1.f / lsum;
#pragma unroll
    for (int r = 0; r < 4; ++r) {
      float li = __shfl(linv, (lane & 48) | (g * 4 + r));
      int row = b * L_SEQ + qr0 + g * 4 + r;
#pragma unroll
      for (int dt = 0; dt < 4; ++dt)
        Ao[(size_t)row * 1024 + h * 64 + dt * 16 + lq] = (bf16)(o[dt][r] * li);
    }
  }
}

extern "C" void kernel_launch(void* const* d_in, const int* in_sizes, int n_in,
                              void* d_out, int out_size, void* d_ws, size_t ws_size,
                              hipStream_t stream) {
  const float* x = (const float*)d_in[0];
  const float* Wqkv = (const float*)d_in[1];
  const float* Wout = (const float*)d_in[2];
  const float* qw = (const float*)d_in[3];
  const float* kw = (const float*)d_in[4];
  float* out = (float*)d_out;

  char* ws = (char*)d_ws;
  size_t off = 0;
  auto alloc = [&](size_t bytes) {
    void* p = ws + off;
    off = (off + bytes + 255) & ~(size_t)255;
    return p;
  };
  bf16* xb = (bf16*)alloc(8388608ull * 2);
  bf16* wqb = (bf16*)alloc(3145728ull * 2);
  bf16* wob = (bf16*)alloc(2097152ull * 2);
  float* qkv = (float*)alloc(4096ull * 1536 * 4);
  bf16* Qb = (bf16*)alloc(4194304ull * 2);
  bf16* Kb = (bf16*)alloc(1048576ull * 2);
  bf16* Vb = (bf16*)alloc(1048576ull * 2);
  bf16* Vt = (bf16*)alloc(1048576ull * 2);
  bf16* Ao = (bf16*)alloc(4194304ull * 2);

  cast_bf16<<<8192, 256, 0, stream>>>(x, xb, 8388608);
  cast_bf16<<<3072, 256, 0, stream>>>(Wqkv, wqb, 3145728);
  cast_bf16<<<2048, 256, 0, stream>>>(Wout, wob, 2097152);
  gemm_bt<<<dim3(12, 32), 256, 0, stream>>>(xb, wqb, qkv, 4096, 1536, 2048);
  norm_rope<<<4096, 256, 0, stream>>>(qkv, qw, kw, Qb, Kb, Vb);
  transpose_v<<<dim3(32, 8), 256, 0, stream>>>(Vb, Vt);
  attn<<<dim3(16, 32), 256, 0, stream>>>(Qb, Kb, Vt, Ao);
  gemm_bt<<<dim3(16, 32), 256, 0, stream>>>(Ao, wob, out, 4096, 2048, 1024);
}

// Round 6
// 271.183 us; speedup vs baseline: 1.6270x; 1.0416x over previous
//
#include <hip/hip_runtime.h>
#include <hip/hip_bf16.h>

// Pipeline: cast->bf16, QKV GEMM (MFMA + global_load_lds + LDS dbuf),
// RMSNorm+RoPE, V-transpose, flash attention (causal, GQA, LDS-staged KV,
// paired q-tiles), output GEMM.

typedef __bf16 bf16;
typedef bf16 bf16x8 __attribute__((ext_vector_type(8)));
typedef bf16 bf16x4 __attribute__((ext_vector_type(4)));
typedef float f32x4 __attribute__((ext_vector_type(4)));

#define L_SEQ 2048
#define NQH 16
#define NKVH 4

// async global->LDS 16B DMA (gfx950). LDS dest is wave-uniform base + lane*16.
typedef __attribute__((address_space(3))) void lds_void;
typedef const __attribute__((address_space(1))) void glb_void;
__device__ __forceinline__ void async_ld16(const void* g, void* l) {
  __builtin_amdgcn_global_load_lds((glb_void*)g, (lds_void*)l, 16, 0, 0);
}

// ---------------- cast fp32 -> bf16, 4 elems/thread ----------------
__global__ __launch_bounds__(256) void cast_bf16(const float* __restrict__ in,
                                                 bf16* __restrict__ out, int n) {
  int i = (blockIdx.x * 256 + threadIdx.x) * 4;
  if (i < n) {
    float4 v = *(const float4*)&in[i];
    bf16x4 o;
    o[0] = (bf16)v.x; o[1] = (bf16)v.y; o[2] = (bf16)v.z; o[3] = (bf16)v.w;
    *(bf16x4*)&out[i] = o;
  }
}

// ---------------- GEMM: C[M,N] = A[M,K] * B[N,K]^T ----------------
// BM=128 x BN (64|128) tile, BK=32, 4 waves, 16x16x32 bf16 MFMA.
// Double-buffered LDS: stage(kt+1 -> buf^1) issued between frag ds_reads and
// MFMAs; ONE __syncthreads per K-step (its vmcnt(0) lands after the loads had
// the whole compute phase in flight). Source chunk pre-swizzled
// (LDS[row][c] holds chunk c ^ ((row>>1)&3)); reads apply the same XOR.
template <int BN>
__global__ __launch_bounds__(256)
void gemm_bt(const bf16* __restrict__ A, const bf16* __restrict__ B,
             float* __restrict__ C, int M, int N, int K) {
  constexpr int ASZ = 128 * 32, BSZ = BN * 32;
  constexpr int BI = BN / 64;   // B staging insts (64->1, 128->2)
  constexpr int NJ = BN / 32;   // n-frags per wave (64->2, 128->4)
  __shared__ bf16 As[2 * ASZ];
  __shared__ bf16 Bs[2 * BSZ];
  const int tid = threadIdx.x;
  const int lane = tid & 63, w = tid >> 6;
  const int lq = lane & 15, g = lane >> 4;
  const int wr = w >> 1, wc = w & 1;
  const int bx = blockIdx.x, by = blockIdx.y;

  const bf16* gA[2];
  bf16* ldsA[2];
  const bf16* gB[BI];
  bf16* ldsB[BI];
#pragma unroll
  for (int c = 0; c < 2; ++c) {
    int slot = c * 256 + tid;
    int row = slot >> 2, ch = slot & 3;
    int sch = ch ^ ((row >> 1) & 3);
    gA[c] = &A[(size_t)(by * 128 + row) * K + sch * 8];
    ldsA[c] = &As[(c * 256 + w * 64) * 8];  // wave-uniform base
  }
#pragma unroll
  for (int c = 0; c < BI; ++c) {
    int slot = c * 256 + tid;
    int row = slot >> 2, ch = slot & 3;
    int sch = ch ^ ((row >> 1) & 3);
    gB[c] = &B[(size_t)(bx * BN + row) * K + sch * 8];
    ldsB[c] = &Bs[(c * 256 + w * 64) * 8];
  }

  auto stage = [&](int kt, int buf) {
#pragma unroll
    for (int c = 0; c < 2; ++c) async_ld16(gA[c] + kt * 32, ldsA[c] + buf * ASZ);
#pragma unroll
    for (int c = 0; c < BI; ++c) async_ld16(gB[c] + kt * 32, ldsB[c] + buf * BSZ);
  };

  f32x4 acc[4][NJ] = {};
  const int nk = K >> 5;
  int cur = 0;

  stage(0, 0);
  __syncthreads();
  for (int kt = 0; kt < nk; ++kt) {
    bf16x8 af[4], bfr[NJ];
#pragma unroll
    for (int i = 0; i < 4; ++i) {
      int ra = wr * 64 + i * 16 + lq;
      af[i] = *(const bf16x8*)&As[cur * ASZ + ra * 32 + (g ^ ((ra >> 1) & 3)) * 8];
    }
#pragma unroll
    for (int j = 0; j < NJ; ++j) {
      int rb = wc * (BN / 2) + j * 16 + lq;
      bfr[j] = *(const bf16x8*)&Bs[cur * BSZ + rb * 32 + (g ^ ((rb >> 1) & 3)) * 8];
    }
    if (kt + 1 < nk) stage(kt + 1, cur ^ 1);  // async into other buffer
#pragma unroll
    for (int i = 0; i < 4; ++i)
#pragma unroll
      for (int j = 0; j < NJ; ++j)
        acc[i][j] = __builtin_amdgcn_mfma_f32_16x16x32_bf16(af[i], bfr[j], acc[i][j], 0, 0, 0);
    __syncthreads();  // drains vmcnt -> buf^1 ready; buf reads all done
    cur ^= 1;
  }
#pragma unroll
  for (int i = 0; i < 4; ++i)
#pragma unroll
    for (int j = 0; j < NJ; ++j) {
      int row = by * 128 + wr * 64 + i * 16 + g * 4;
      int col = bx * BN + wc * (BN / 2) + j * 16 + lq;
#pragma unroll
      for (int r = 0; r < 4; ++r) C[(size_t)(row + r) * N + col] = acc[i][j][r];
    }
}

// ---------------- RMSNorm + RoPE + split/scale ----------------
__global__ __launch_bounds__(256)
void norm_rope(const float* __restrict__ qkv, const float* __restrict__ qw,
               const float* __restrict__ kw, bf16* __restrict__ Qb,
               bf16* __restrict__ Kb, bf16* __restrict__ Vb) {
  const int bl = blockIdx.x;  // b*L + l
  const int b = bl >> 11, l = bl & (L_SEQ - 1);
  const int w = threadIdx.x >> 6, lane = threadIdx.x & 63;
  const int i = lane & 31;
  float freq = exp2f(-(float)i * 0.41524101186280154f);
  float theta = (float)l * freq;
  float sn, cs;
  sincosf(theta, &sn, &cs);
  float qwl = qw[lane], kwl = kw[lane];

  for (int h = w; h < 24; h += 4) {
    float v = qkv[(size_t)bl * 1536 + h * 64 + lane];
    if (h < 20) {
      float ss = v * v;
#pragma unroll
      for (int off = 32; off; off >>= 1) ss += __shfl_xor(ss, off);
      float rs = rsqrtf(ss * (1.f / 64.f) + 1e-6f);
      float wt = (h < 16) ? qwl : kwl;
      float y = v * rs * wt;
      float part = __shfl_xor(y, 32);
      float out = (lane < 32) ? (y * cs - part * sn) : (part * sn + y * cs);
      if (h < 16)
        Qb[((size_t)(b * NQH + h) * L_SEQ + l) * 64 + lane] = (bf16)(out * 0.125f);
      else
        Kb[((size_t)(b * NKVH + (h - 16)) * L_SEQ + l) * 64 + lane] = (bf16)out;
    } else {
      Vb[((size_t)(b * NKVH + (h - 20)) * L_SEQ + l) * 64 + lane] = (bf16)v;
    }
  }
}

// ---------------- V transpose: (bk, L, 64) -> (bk, 64, L) ----------------
__global__ __launch_bounds__(256)
void transpose_v(const bf16* __restrict__ Vb, bf16* __restrict__ Vt) {
  __shared__ bf16 T[64 * 66];
  const int bk = blockIdx.y;
  const int l0 = blockIdx.x * 64;
  const int t = threadIdx.x;
  const bf16* src = Vb + (size_t)bk * L_SEQ * 64;
#pragma unroll
  for (int c = 0; c < 2; ++c) {
    int idx = c * 256 + t;
    int row = idx >> 3, ch = idx & 7;
    bf16x8 v = *(const bf16x8*)&src[(size_t)(l0 + row) * 64 + ch * 8];
#pragma unroll
    for (int j = 0; j < 8; ++j) T[(ch * 8 + j) * 66 + row] = v[j];
  }
  __syncthreads();
  bf16* dst = Vt + (size_t)bk * 64 * L_SEQ;
#pragma unroll
  for (int c = 0; c < 2; ++c) {
    int idx = c * 256 + t;
    int d = idx >> 3, ch = idx & 7;
    bf16x8 v;
#pragma unroll
    for (int j = 0; j < 8; ++j) v[j] = T[d * 66 + ch * 8 + j];
    *(bf16x8*)&dst[(size_t)d * L_SEQ + l0 + ch * 8] = v;
  }
}

// ---------------- flash attention, causal, GQA, LDS-staged KV ----------------
// block = 4 waves, 16 q-rows/wave; 64-key LDS tiles (T14 async-split staging,
// XOR-swizzled rows). Each block processes the q-tile PAIR (p, 31-p) serially
// => uniform 33 key-tiles/block, grid 16x32, no triangular tail.
__global__ __launch_bounds__(256)
void attn(const bf16* __restrict__ Qb, const bf16* __restrict__ Kb,
          const bf16* __restrict__ Vt, bf16* __restrict__ Ao) {
  const int pair = blockIdx.x;  // 0..15
  const int bh = blockIdx.y;    // 0..31
  const int b = bh >> 4, h = bh & 15, kv = h >> 2;
  const int tid = threadIdx.x;
  const int w = tid >> 6, lane = tid & 63;
  const int lq = lane & 15, g = lane >> 4;

  __shared__ bf16 Ks[64][64];       // [key][dim], swizzled chunks
  __shared__ bf16 Vs[64][64];       // [dim][key], swizzled chunks
  __shared__ bf16 Plds[4][16][72];  // per-wave P bounce

  const bf16* Qp = Qb + (size_t)(b * NQH + h) * L_SEQ * 64;
  const bf16* Kp = Kb + (size_t)(b * NKVH + kv) * L_SEQ * 64;
  const bf16* Vp = Vt + (size_t)(b * NKVH + kv) * 64 * L_SEQ;

  // staging thread mapping: 512 chunk-slots of 16B; r = idx>>3 (row), c = idx&7
  const int sr0 = tid >> 3, sc = tid & 7;
  const int sr1 = sr0 + 32;
  const int swc0 = (sc ^ (sr0 & 7)) * 8;  // sr1&7 == sr0&7
  bf16x8 rk0, rk1, rv0, rv1;

  auto load_tile = [&](int k0) {
    rk0 = *(const bf16x8*)&Kp[(size_t)(k0 + sr0) * 64 + sc * 8];
    rk1 = *(const bf16x8*)&Kp[(size_t)(k0 + sr1) * 64 + sc * 8];
    rv0 = *(const bf16x8*)&Vp[(size_t)sr0 * L_SEQ + k0 + sc * 8];
    rv1 = *(const bf16x8*)&Vp[(size_t)sr1 * L_SEQ + k0 + sc * 8];
  };
  auto write_tile = [&]() {
    *(bf16x8*)&Ks[sr0][swc0] = rk0;
    *(bf16x8*)&Ks[sr1][swc0] = rk1;
    *(bf16x8*)&Vs[sr0][swc0] = rv0;
    *(bf16x8*)&Vs[sr1][swc0] = rv1;
  };

  const float L2E = 1.4426950408889634f;

  for (int half = 0; half < 2; ++half) {
    const int qblk = half ? (31 - pair) : pair;
    const int qr0 = qblk * 64 + w * 16;
    const int qg = qr0 + lq;  // this lane's query row (global)

    bf16x8 qf[2];
    qf[0] = *(const bf16x8*)&Qp[(qr0 + lq) * 64 + g * 8];
    qf[1] = *(const bf16x8*)&Qp[(qr0 + lq) * 64 + 32 + g * 8];

    f32x4 o[4] = {};
    float m = -1e30f, lsum = 0.f;

    const int nkt = qblk + 1;
    load_tile(0);
    __syncthreads();  // prior half's LDS readers done before overwrite
    write_tile();
    __syncthreads();

    for (int kt = 0; kt < nkt; ++kt) {
      const int k0 = kt * 64;
      const bool diag = (kt == nkt - 1);
      if (kt + 1 < nkt) load_tile(k0 + 64);  // async: hides under compute

      // ---- QK^T: s[ks] holds scores for query lq, keys k0+ks*16+g*4+r ----
      f32x4 s[4] = {};
#pragma unroll
      for (int ks = 0; ks < 4; ++ks) {
        if (!diag || ks <= w) {  // skip fully-masked frags on diag tile
          const int row = ks * 16 + lq, sw = lq & 7;
          bf16x8 kf0 = *(const bf16x8*)&Ks[row][(g ^ sw) * 8];
          bf16x8 kf1 = *(const bf16x8*)&Ks[row][((g + 4) ^ sw) * 8];
          s[ks] = __builtin_amdgcn_mfma_f32_16x16x32_bf16(kf0, qf[0], s[ks], 0, 0, 0);
          s[ks] = __builtin_amdgcn_mfma_f32_16x16x32_bf16(kf1, qf[1], s[ks], 0, 0, 0);
        }
      }
      // ---- mask (diag tile only) + online softmax ----
      if (diag) {
#pragma unroll
        for (int ks = 0; ks < 4; ++ks)
#pragma unroll
          for (int r = 0; r < 4; ++r)
            if (k0 + ks * 16 + g * 4 + r > qg) s[ks][r] = -1e30f;
      }
      float tmax = -1e30f;
#pragma unroll
      for (int ks = 0; ks < 4; ++ks)
#pragma unroll
        for (int r = 0; r < 4; ++r) tmax = fmaxf(tmax, s[ks][r]);
      tmax = fmaxf(tmax, __shfl_xor(tmax, 16));
      tmax = fmaxf(tmax, __shfl_xor(tmax, 32));
      float mnew = fmaxf(m, tmax);
      float alpha = exp2f((m - mnew) * L2E);
      m = mnew;
      float rsum = 0.f;
#pragma unroll
      for (int ks = 0; ks < 4; ++ks) {
        bf16x4 p;
#pragma unroll
        for (int r = 0; r < 4; ++r) {
          float pv = exp2f((s[ks][r] - mnew) * L2E);
          rsum += pv;
          p[r] = (bf16)pv;
        }
        *(bf16x4*)&Plds[w][lq][ks * 16 + g * 4] = p;
      }
      rsum += __shfl_xor(rsum, 16);
      rsum += __shfl_xor(rsum, 32);
      lsum = lsum * alpha + rsum;

      // ---- rescale O (rows are queries g*4+r) ----
      float ar[4];
#pragma unroll
      for (int r = 0; r < 4; ++r) ar[r] = __shfl(alpha, (lane & 48) | (g * 4 + r));
#pragma unroll
      for (int dt = 0; dt < 4; ++dt)
#pragma unroll
        for (int r = 0; r < 4; ++r) o[dt][r] *= ar[r];

      // ---- PV: o[dt] += P[16x64] * V[64 keys, dims dt*16..+15] ----
      bf16x8 pf0 = *(const bf16x8*)&Plds[w][lq][g * 8];
      bf16x8 pf1 = *(const bf16x8*)&Plds[w][lq][32 + g * 8];
#pragma unroll
      for (int dt = 0; dt < 4; ++dt) {
        const int row = dt * 16 + lq, sw = lq & 7;
        bf16x8 vf0 = *(const bf16x8*)&Vs[row][(g ^ sw) * 8];
        o[dt] = __builtin_amdgcn_mfma_f32_16x16x32_bf16(pf0, vf0, o[dt], 0, 0, 0);
        if (!diag || w >= 2) {
          bf16x8 vf1 = *(const bf16x8*)&Vs[row][((g + 4) ^ sw) * 8];
          o[dt] = __builtin_amdgcn_mfma_f32_16x16x32_bf16(pf1, vf1, o[dt], 0, 0, 0);
        }
      }

      if (kt + 1 < nkt) {
        __syncthreads();   // all waves done reading LDS tile kt
        write_tile();      // vmcnt wait + ds_write of tile kt+1
        __syncthreads();   // tile kt+1 visible
      }
    }

    float linv = 1.f / lsum;
#pragma unroll
    for (int r = 0; r < 4; ++r) {
      float li = __shfl(linv, (lane & 48) | (g * 4 + r));
      int row = b * L_SEQ + qr0 + g * 4 + r;
#pragma unroll
      for (int dt = 0; dt < 4; ++dt)
        Ao[(size_t)row * 1024 + h * 64 + dt * 16 + lq] = (bf16)(o[dt][r] * li);
    }
  }
}

extern "C" void kernel_launch(void* const* d_in, const int* in_sizes, int n_in,
                              void* d_out, int out_size, void* d_ws, size_t ws_size,
                              hipStream_t stream) {
  const float* x = (const float*)d_in[0];
  const float* Wqkv = (const float*)d_in[1];
  const float* Wout = (const float*)d_in[2];
  const float* qw = (const float*)d_in[3];
  const float* kw = (const float*)d_in[4];
  float* out = (float*)d_out;

  char* ws = (char*)d_ws;
  size_t off = 0;
  auto alloc = [&](size_t bytes) {
    void* p = ws + off;
    off = (off + bytes + 255) & ~(size_t)255;
    return p;
  };
  bf16* xb = (bf16*)alloc(8388608ull * 2);
  bf16* wqb = (bf16*)alloc(3145728ull * 2);
  bf16* wob = (bf16*)alloc(2097152ull * 2);
  float* qkv = (float*)alloc(4096ull * 1536 * 4);
  bf16* Qb = (bf16*)alloc(4194304ull * 2);
  bf16* Kb = (bf16*)alloc(1048576ull * 2);
  bf16* Vb = (bf16*)alloc(1048576ull * 2);
  bf16* Vt = (bf16*)alloc(1048576ull * 2);
  bf16* Ao = (bf16*)alloc(4194304ull * 2);

  cast_bf16<<<8192, 256, 0, stream>>>(x, xb, 8388608);
  cast_bf16<<<3072, 256, 0, stream>>>(Wqkv, wqb, 3145728);
  cast_bf16<<<2048, 256, 0, stream>>>(Wout, wob, 2097152);
  gemm_bt<64><<<dim3(24, 32), 256, 0, stream>>>(xb, wqb, qkv, 4096, 1536, 2048);
  norm_rope<<<4096, 256, 0, stream>>>(qkv, qw, kw, Qb, Kb, Vb);
  transpose_v<<<dim3(32, 8), 256, 0, stream>>>(Vb, Vt);
  attn<<<dim3(16, 32), 256, 0, stream>>>(Qb, Kb, Vt, Ao);
  gemm_bt<128><<<dim3(16, 32), 256, 0, stream>>>(Ao, wob, out, 4096, 2048, 1024);
}